// Round 7
// baseline (262.159 us; speedup 1.0000x reference)
//
#include <hip/hip_runtime.h>

#define B_ 2
#define S_ 2048
#define E_ 1024
#define H_ 16
#define D_ 64

typedef short  s16x8 __attribute__((ext_vector_type(8)));
typedef float  f32x4 __attribute__((ext_vector_type(4)));
typedef unsigned short u16x4 __attribute__((ext_vector_type(4)));

__device__ __forceinline__ ushort f2bf(float f) {
    union { float f; unsigned u; } x; x.f = f;
    unsigned u = x.u + 0x7fffu + ((x.u >> 16) & 1u);   // RNE
    return (ushort)(u >> 16);
}

// ---------------------------------------------------------------------------
// Merged prep: blocks [0,4096): X->bf16; [4096,4864): Wqkv transpose;
// [4864,5120): Wproj transpose. Branch is block-uniform.
// ---------------------------------------------------------------------------
__global__ __launch_bounds__(256) void prep_kernel(
    const float* __restrict__ X, ushort* __restrict__ Xbf,
    const float* __restrict__ Wqkv, ushort* __restrict__ Wqkvt,
    const float* __restrict__ Wproj, ushort* __restrict__ Wprojt)
{
    __shared__ float tile[64][65];
    int blk = blockIdx.x;
    int tid = threadIdx.x;
    if (blk < 4096) {
        int i = blk * 1024 + tid * 4;
        float4 v = *(const float4*)&X[i];
        u16x4 o;
        o.x = f2bf(v.x); o.y = f2bf(v.y); o.z = f2bf(v.z); o.w = f2bf(v.w);
        *(u16x4*)&Xbf[i] = o;
        return;
    }
    const float* W; ushort* Wt; int Kdim, Ndim, n0, k0;
    if (blk < 4096 + 768) {
        int bb = blk - 4096;
        W = Wqkv; Wt = Wqkvt; Kdim = E_; Ndim = 3 * E_;
        n0 = (bb % 48) * 64; k0 = (bb / 48) * 64;
    } else {
        int bb = blk - 4864;
        W = Wproj; Wt = Wprojt; Kdim = E_; Ndim = E_;
        n0 = (bb % 16) * 64; k0 = (bb / 16) * 64;
    }
    int c = tid & 63;
#pragma unroll
    for (int r = tid >> 6; r < 64; r += 4)
        tile[r][c] = W[(size_t)(k0 + r) * Ndim + n0 + c];
    __syncthreads();
#pragma unroll
    for (int r = tid >> 6; r < 64; r += 4)
        Wt[(size_t)(n0 + r) * Kdim + k0 + c] = f2bf(tile[c][r]);
}

// ---------------------------------------------------------------------------
// bf16 MFMA GEMM (m97 structure): C[m][n] = sum_k A[m][k]*Bt[n][k] + bias[n]
// 128x128 tile, BK=32, global_load_lds w=16, ds_read_b128 frags.
// mode 0: fp32 C0. mode 1 (N=3E): seg0->Qbf, seg1->Kf32+Kbf, seg2->Vf32.
// ---------------------------------------------------------------------------
__global__ __launch_bounds__(256) void gemm_mfma_bt(
    const ushort* __restrict__ A,    // [M][K] bf16
    const ushort* __restrict__ Bt,   // [N][K] bf16
    const float* __restrict__ bias,  // [N]
    int M, int N, int K,
    float* __restrict__ C0,
    ushort* __restrict__ Qbf, float* __restrict__ Kf32, ushort* __restrict__ Kbf,
    float* __restrict__ Vf32, int mode)
{
    __shared__ ushort As[128 * 32];
    __shared__ ushort Bs[128 * 32];
    int tid = threadIdx.x;
    int wid = tid >> 6, lane = tid & 63;
    int l15 = lane & 15, quad = lane >> 4;
    int wm = wid >> 1, wn = wid & 1;
    int row0 = blockIdx.y * 128, col0 = blockIdx.x * 128;

    int sr = wid * 16 + (lane >> 2);
    int sk = (lane & 3) * 8;

    f32x4 acc[4][4];
#pragma unroll
    for (int mt = 0; mt < 4; mt++)
#pragma unroll
        for (int nt = 0; nt < 4; nt++) acc[mt][nt] = (f32x4){0.f, 0.f, 0.f, 0.f};

    for (int k0 = 0; k0 < K; k0 += 32) {
        __syncthreads();
#pragma unroll
        for (int c = 0; c < 2; c++) {
            int r = c * 64 + sr;
            __builtin_amdgcn_global_load_lds(
                (const __attribute__((address_space(1))) unsigned int*)
                    &A[(size_t)(row0 + r) * K + k0 + sk],
                (__attribute__((address_space(3))) unsigned int*)&As[r * 32 + sk],
                16, 0, 0);
            __builtin_amdgcn_global_load_lds(
                (const __attribute__((address_space(1))) unsigned int*)
                    &Bt[(size_t)(col0 + r) * K + k0 + sk],
                (__attribute__((address_space(3))) unsigned int*)&Bs[r * 32 + sk],
                16, 0, 0);
        }
        __syncthreads();

        s16x8 af[4], bf[4];
#pragma unroll
        for (int mt = 0; mt < 4; mt++)
            af[mt] = *(const s16x8*)&As[(wm * 64 + mt * 16 + l15) * 32 + quad * 8];
#pragma unroll
        for (int nt = 0; nt < 4; nt++)
            bf[nt] = *(const s16x8*)&Bs[(wn * 64 + nt * 16 + l15) * 32 + quad * 8];
#pragma unroll
        for (int mt = 0; mt < 4; mt++)
#pragma unroll
            for (int nt = 0; nt < 4; nt++)
                acc[mt][nt] = __builtin_amdgcn_mfma_f32_16x16x32_bf16(
                    af[mt], bf[nt], acc[mt][nt], 0, 0, 0);
    }

#pragma unroll
    for (int nt = 0; nt < 4; nt++) {
        int n = col0 + wn * 64 + nt * 16 + l15;
        float bv = bias[n];
        if (mode == 1) {
            int seg = n >> 10;
            int nn = n & (E_ - 1);
#pragma unroll
            for (int mt = 0; mt < 4; mt++)
#pragma unroll
                for (int r = 0; r < 4; r++) {
                    int row = row0 + wm * 64 + mt * 16 + quad * 4 + r;
                    float v = acc[mt][nt][r] + bv;
                    size_t idx = (size_t)row * E_ + nn;
                    if (seg == 0)      Qbf[idx] = f2bf(v);
                    else if (seg == 1) { Kf32[idx] = v; Kbf[idx] = f2bf(v); }
                    else               Vf32[idx] = v;
                }
        } else {
#pragma unroll
            for (int mt = 0; mt < 4; mt++)
#pragma unroll
                for (int r = 0; r < 4; r++) {
                    int row = row0 + wm * 64 + mt * 16 + quad * 4 + r;
                    C0[(size_t)row * N + n] = acc[mt][nt][r] + bv;
                }
        }
    }
}

// ---------------------------------------------------------------------------
// V transpose: fp32 V [b*S+s][h*64+d] -> bf16 Vt [(b*H+h)*64+d][s]
// ---------------------------------------------------------------------------
__global__ __launch_bounds__(256) void vtrans_kernel(
    const float* __restrict__ V, ushort* __restrict__ Vt)
{
    __shared__ float tile[64][65];
    int blk = blockIdx.x;
    int s0 = (blk & 31) * 64;
    int bh = blk >> 5;
    int b = bh >> 4, h = bh & 15;
    int tid = threadIdx.x;
    int d = tid & 63;
#pragma unroll
    for (int i = tid >> 6; i < 64; i += 4)
        tile[i][d] = V[((size_t)(b * S_ + s0 + i)) * E_ + h * 64 + d];
    __syncthreads();
    int lane = tid & 63, w = tid >> 6;
#pragma unroll
    for (int dd = w; dd < 64; dd += 4)
        Vt[((size_t)(bh * 64 + dd)) * S_ + s0 + lane] = f2bf(tile[lane][dd]);
}

// ---------------------------------------------------------------------------
// MFMA flash attention, fixed-reference softmax, TRANSPOSED score path.
// Wave = 32 q-rows (two 16-row A-frags); block = 4 waves = 128 q-rows.
// Blocks pair q-tiles (15-pr, pr) -> 34 key-tile-units each, 256 blocks.
// St = K*Q^T (A=K-frag from Ks, B=Q-frag in regs): C-layout gives q=l15,
// key=quad*4+r  ->  P stores as Ps[q][key] with 4 contiguous keys per reg
// quad: 8 ds_write_b64 per wave-tile (vs 32 b16), bias reads as dwordx4.
// PV: A=P (Ps rows contiguous b128), B=V (Vs[d][key] rows) — O in C-layout.
// Row-sums: per-lane (q=l15) accumulate; 2 shuffles once per q-tile.
// ---------------------------------------------------------------------------
__global__ __launch_bounds__(256) void attn_mfma_kernel(
    const ushort* __restrict__ Qbf,  // [B*S, E] bf16
    const ushort* __restrict__ Kbf,  // [B*S, E] bf16
    const ushort* __restrict__ Vt,   // [(b*H+h)*64+d][S] bf16
    const float* __restrict__ bias,  // [S,S]
    ushort* __restrict__ Ctx)        // [B*S, E] bf16
{
    __shared__ ushort Ks[64][72];    // [key][d]
    __shared__ ushort Vs[64][72];    // [d][key]
    __shared__ ushort Ps[4][32][72]; // per-wave P [q][key]

    int blk = blockIdx.x;
    int bh = blk & 31;
    int pr = blk >> 5;               // 0..7
    int b = bh >> 4, h = bh & 15;
    int tid = threadIdx.x;
    int wid = tid >> 6, lane = tid & 63;
    int l15 = lane & 15, quad = lane >> 4;

    int skey = tid >> 2;
    int scol = (tid & 3) * 16;
    const float scale = 0.125f;

    const size_t krow = (size_t)(b * S_ + skey) * E_ + h * 64 + scol; // + j0*E_
    const size_t vrow = (size_t)(bh * 64 + skey) * S_ + scol;        // + j0

    for (int half = 0; half < 2; half++) {
        int qt = half ? pr : (15 - pr);        // 128-row q-tile index
        int q0w = qt * 128 + wid * 32;
        int ntiles = 2 * qt + 2;

        // Q fragments: sub-tiles m=0,1 (rows q0w+m*16+l15)
        s16x8 qa0[2], qa1[2];
#pragma unroll
        for (int m = 0; m < 2; m++) {
            size_t qb = (size_t)(b * S_ + q0w + m * 16 + l15) * E_ + h * 64 + quad * 8;
            qa0[m] = *(const s16x8*)&Qbf[qb];
            qa1[m] = *(const s16x8*)&Qbf[qb + 32];
        }

        f32x4 o[2][4];
#pragma unroll
        for (int m = 0; m < 2; m++)
#pragma unroll
            for (int dt = 0; dt < 4; dt++) o[m][dt] = (f32x4){0.f, 0.f, 0.f, 0.f};
        float lsum[2] = {0.f, 0.f};

        // preload tile 0: K/V staging regs + bias (dwordx4)
        float4 kr0 = ((const float4*)&Kbf[krow])[0];
        float4 kr1 = ((const float4*)&Kbf[krow])[1];
        float4 vr0 = ((const float4*)&Vt[vrow])[0];
        float4 vr1 = ((const float4*)&Vt[vrow])[1];
        f32x4 bvn[2][4];
#pragma unroll
        for (int m = 0; m < 2; m++)
#pragma unroll
            for (int kt = 0; kt < 4; kt++)
                bvn[m][kt] = *(const f32x4*)&bias[(size_t)(q0w + m * 16 + l15) * S_ + kt * 16 + quad * 4];

        for (int t = 0; t < ntiles; t++) {
            int j0 = t * 64;
            __syncthreads();           // prior tile's LDS reads done
            *(float4*)&Ks[skey][scol]     = kr0;
            *(float4*)&Ks[skey][scol + 8] = kr1;
            *(float4*)&Vs[skey][scol]     = vr0;
            *(float4*)&Vs[skey][scol + 8] = vr1;
            __syncthreads();

            // prefetch K/V for t+1 (regs; hides under this tile's compute)
            if (t + 1 < ntiles) {
                int j1 = j0 + 64;
                kr0 = ((const float4*)&Kbf[krow + (size_t)j1 * E_])[0];
                kr1 = ((const float4*)&Kbf[krow + (size_t)j1 * E_])[1];
                vr0 = ((const float4*)&Vt[vrow + j1])[0];
                vr1 = ((const float4*)&Vt[vrow + j1])[1];
            }

            // ---- St = K Q^T : per kt, rows key=quad*4+r, cols q=l15
            f32x4 s[2][4];
#pragma unroll
            for (int kt = 0; kt < 4; kt++) {
                s16x8 kb0 = *(const s16x8*)&Ks[kt * 16 + l15][quad * 8];
                s16x8 kb1 = *(const s16x8*)&Ks[kt * 16 + l15][quad * 8 + 32];
#pragma unroll
                for (int m = 0; m < 2; m++) {
                    f32x4 a = (f32x4){0.f, 0.f, 0.f, 0.f};
                    a = __builtin_amdgcn_mfma_f32_16x16x32_bf16(kb0, qa0[m], a, 0, 0, 0);
                    s[m][kt] = __builtin_amdgcn_mfma_f32_16x16x32_bf16(kb1, qa1[m], a, 0, 0, 0);
                }
            }

            // ---- p = exp(s*scale + bias); causal -> 0; b64 writes to Ps
            bool diag = (t >= 2 * qt);
#pragma unroll
            for (int m = 0; m < 2; m++) {
                int row = q0w + m * 16 + l15;
#pragma unroll
                for (int kt = 0; kt < 4; kt++) {
                    f32x4 bb = bvn[m][kt];
                    u16x4 pk;
#pragma unroll
                    for (int r = 0; r < 4; r++) {
                        int j = j0 + kt * 16 + quad * 4 + r;
                        float v = s[m][kt][r] * scale + bb[r];
                        float p = (diag && j > row) ? 0.f : __expf(v);
                        lsum[m] += p;
                        pk[r] = f2bf(p);
                    }
                    *(u16x4*)&Ps[wid][m * 16 + l15][kt * 16 + quad * 4] = pk;
                }
            }

            // prefetch bias for t+1 (consumed after next tile's QK^T)
            if (t + 1 < ntiles) {
                int j1 = j0 + 64;
#pragma unroll
                for (int m = 0; m < 2; m++)
#pragma unroll
                    for (int kt = 0; kt < 4; kt++)
                        bvn[m][kt] = *(const f32x4*)&bias[(size_t)(q0w + m * 16 + l15) * S_ + j1 + kt * 16 + quad * 4];
            }

            // ---- O += P V  (Ps wave-private; same-wave dep -> no barrier)
            s16x8 pa0[2], pa1[2];
#pragma unroll
            for (int m = 0; m < 2; m++) {
                pa0[m] = *(const s16x8*)&Ps[wid][m * 16 + l15][quad * 8];
                pa1[m] = *(const s16x8*)&Ps[wid][m * 16 + l15][quad * 8 + 32];
            }
#pragma unroll
            for (int dt = 0; dt < 4; dt++) {
                s16x8 vb0 = *(const s16x8*)&Vs[dt * 16 + l15][quad * 8];
                s16x8 vb1 = *(const s16x8*)&Vs[dt * 16 + l15][quad * 8 + 32];
#pragma unroll
                for (int m = 0; m < 2; m++) {
                    o[m][dt] = __builtin_amdgcn_mfma_f32_16x16x32_bf16(pa0[m], vb0, o[m][dt], 0, 0, 0);
                    o[m][dt] = __builtin_amdgcn_mfma_f32_16x16x32_bf16(pa1[m], vb1, o[m][dt], 0, 0, 0);
                }
            }
        }

        // ---- epilogue: reduce row sums across quads (q=l15), redistribute
#pragma unroll
        for (int m = 0; m < 2; m++) {
            float l = lsum[m];
            l += __shfl_xor(l, 16);
            l += __shfl_xor(l, 32);
            float inv = 1.f / l;      // valid for q = q0w + m*16 + l15
#pragma unroll
            for (int r = 0; r < 4; r++) {
                float invr = __shfl(inv, quad * 4 + r);   // lane with l15=quad*4+r
                int row = q0w + m * 16 + quad * 4 + r;
#pragma unroll
                for (int dt = 0; dt < 4; dt++)
                    Ctx[((size_t)(b * S_ + row)) * E_ + h * 64 + dt * 16 + l15] =
                        f2bf(o[m][dt][r] * invr);
            }
        }
    }
}

// ---------------------------------------------------------------------------
extern "C" void kernel_launch(void* const* d_in, const int* in_sizes, int n_in,
                              void* d_out, int out_size, void* d_ws, size_t ws_size,
                              hipStream_t stream) {
    const float* X     = (const float*)d_in[0];
    const float* abias = (const float*)d_in[1];
    const float* Wqkv  = (const float*)d_in[2];
    const float* bqkv  = (const float*)d_in[3];
    const float* Wproj = (const float*)d_in[4];
    const float* bproj = (const float*)d_in[5];

    const size_t plane = (size_t)B_ * S_ * E_;   // 4,194,304
    float* out  = (float*)d_out;
    float* kout = out + plane;                   // cache_key (fp32 output)
    float* vout = kout + plane;                  // cache_value (fp32 output)

    // workspace: 4 bf16 planes + weights = 42 MB (proven footprint).
    // ctxbf ALIASES xbf (X's bf16 copy is dead after the QKV GEMM).
    ushort* xbf    = (ushort*)d_ws;
    ushort* qbf    = xbf + plane;
    ushort* kbf    = qbf + plane;
    ushort* vt     = kbf + plane;
    ushort* ctxbf  = xbf;                        // alias (see above)
    ushort* wqkvt  = vt + plane;                 // [3E][E]
    ushort* wprojt = wqkvt + (size_t)3 * E_ * E_;// [E][E]

    const int M = B_ * S_;

    // merged prep: X cast + both weight transposes
    prep_kernel<<<dim3(4096 + 768 + 256), 256, 0, stream>>>(
        X, xbf, Wqkv, wqkvt, Wproj, wprojt);

    gemm_mfma_bt<<<dim3(3 * E_ / 128, M / 128), 256, 0, stream>>>(
        xbf, wqkvt, bqkv, M, 3 * E_, E_,
        nullptr, qbf, kout, kbf, vout, 1);

    vtrans_kernel<<<dim3(B_ * H_ * (S_ / 64)), 256, 0, stream>>>(vout, vt);

    // flash attention: 256 perfectly-balanced blocks (34 tile-units each)
    attn_mfma_kernel<<<dim3(B_ * H_ * 8), 256, 0, stream>>>(
        qbf, kbf, vt, abias, ctxbf);

    gemm_mfma_bt<<<dim3(E_ / 128, M / 128), 256, 0, stream>>>(
        ctxbf, wprojt, bproj, M, E_, E_,
        out, nullptr, nullptr, nullptr, nullptr, 0);
}